// Round 5
// baseline (803.659 us; speedup 1.0000x reference)
//
#include <hip/hip_runtime.h>

#define N_NODES 50000
#define E_EDGES 800000
#define IN_DIM 256
#define H_HEADS 4
#define F_OUT 64
#define EF_DIM 64
#define NT_TYPES 8
#define SLOPE 0.2f
#define HF 256  /* H*F */

#define NBLK 512               /* persistent grid: 2 blocks/CU guaranteed by launch_bounds(256,3) */
#define CHUNK 98               /* ceil(N/NBLK) <= 128 */
#define MAGIC 0x13579BDF

typedef __attribute__((ext_vector_type(8))) short short8;
typedef __attribute__((ext_vector_type(4))) float f32x4;
typedef unsigned short ushort_t;

// workspace layout (float element offsets)
#define FEATBF_OFF 0          /* N*HF bf16 = 6.4M floats */
#define EL_OFF   6400000
#define ER_OFF   6600000
#define EE_OFF   6800000
#define BT_OFF   6800064      /* 256x256 bf16 = 32768 floats */
#define INT_OFF  6832832
// int offsets within int region
#define DEG_IOFF     0        /* 50,000 */
#define CURSOR_IOFF  50000    /* 50,000 (adjacent: zeroed together) */
#define ROWOFF_IOFF  100000   /* 50,001 -> pad 50,008 */
#define SSRC_IOFF    150008
#define SETY_IOFF    950008
#define EID_IOFF     1750008
#define BAR_IOFF     2550008  /* bar[0]=gen bar[1..32]=sub bar[33]=root bar[34]=flag */
#define PART_IOFF    2550048  /* NBLK partials */

__device__ __forceinline__ ushort_t f2bf(float f) {
    unsigned u = __float_as_uint(f);
    u += 0x7fffu + ((u >> 16) & 1u);
    return (ushort_t)(u >> 16);
}
__device__ __forceinline__ float bf2f(ushort_t b) {
    return __uint_as_float(((unsigned)b) << 16);
}

// ---------------- device-scope grid barrier (tree: 32 sub-counters) ----------------
__device__ __forceinline__ void bar_sync(int* bar) {
    __syncthreads();
    if (threadIdx.x == 0) {
        __threadfence();
        const int sub = blockIdx.x & 31;
        const int g = __hip_atomic_load(bar, __ATOMIC_ACQUIRE, __HIP_MEMORY_SCOPE_AGENT);
        const int v = __hip_atomic_fetch_add(bar + 1 + sub, 1, __ATOMIC_ACQ_REL, __HIP_MEMORY_SCOPE_AGENT);
        if (v == (NBLK / 32) - 1) {
            __hip_atomic_store(bar + 1 + sub, 0, __ATOMIC_RELAXED, __HIP_MEMORY_SCOPE_AGENT);
            const int r = __hip_atomic_fetch_add(bar + 33, 1, __ATOMIC_ACQ_REL, __HIP_MEMORY_SCOPE_AGENT);
            if (r == 31) {
                __hip_atomic_store(bar + 33, 0, __ATOMIC_RELAXED, __HIP_MEMORY_SCOPE_AGENT);
                __hip_atomic_fetch_add(bar, 1, __ATOMIC_RELEASE, __HIP_MEMORY_SCOPE_AGENT);
            }
        }
        while (__hip_atomic_load(bar, __ATOMIC_ACQUIRE, __HIP_MEMORY_SCOPE_AGENT) == g)
            __builtin_amdgcn_s_sleep(2);
        __threadfence();
    }
    __syncthreads();
}

// ---------------- MFMA GEMM tile body (64 rows x 256 cols per tile) ----------------
__device__ __forceinline__ void gemm_body(
    const float* __restrict__ nfeat, const ushort_t* __restrict__ Bt,
    const float* __restrict__ attn_l, const float* __restrict__ attn_r,
    ushort_t* __restrict__ feat, float* __restrict__ el, float* __restrict__ er,
    int blk)
{
    const int w    = threadIdx.x >> 6;
    const int lane = threadIdx.x & 63;
    const int n16  = lane & 15;
    const int quad = lane >> 4;
    const int row0 = blk * 64;

    f32x4 acc[4][4];
    #pragma unroll
    for (int rt = 0; rt < 4; rt++)
        #pragma unroll
        for (int ct = 0; ct < 4; ct++)
            acc[rt][ct] = (f32x4){0.f, 0.f, 0.f, 0.f};

    for (int kb = 0; kb < IN_DIM; kb += 32) {
        short8 a[4], b[4];
        #pragma unroll
        for (int rt = 0; rt < 4; rt++) {
            int r = row0 + rt * 16 + n16;
            r = r < N_NODES ? r : N_NODES - 1;
            const float* p = nfeat + (size_t)r * IN_DIM + kb + quad * 8;
            const float4 v0 = *(const float4*)p;
            const float4 v1 = *(const float4*)(p + 4);
            short8 t;
            t[0] = (short)f2bf(v0.x); t[1] = (short)f2bf(v0.y);
            t[2] = (short)f2bf(v0.z); t[3] = (short)f2bf(v0.w);
            t[4] = (short)f2bf(v1.x); t[5] = (short)f2bf(v1.y);
            t[6] = (short)f2bf(v1.z); t[7] = (short)f2bf(v1.w);
            a[rt] = t;
        }
        #pragma unroll
        for (int ct = 0; ct < 4; ct++) {
            const int c = w * 64 + ct * 16 + n16;
            b[ct] = *(const short8*)(Bt + (size_t)c * 256 + kb + quad * 8);
        }
        #pragma unroll
        for (int rt = 0; rt < 4; rt++)
            #pragma unroll
            for (int ct = 0; ct < 4; ct++)
                acc[rt][ct] = __builtin_amdgcn_mfma_f32_16x16x32_bf16(a[rt], b[ct], acc[rt][ct], 0, 0, 0);
    }

    float alv[4], arv[4];
    #pragma unroll
    for (int ct = 0; ct < 4; ct++) {
        alv[ct] = attn_l[w * 64 + ct * 16 + n16];
        arv[ct] = attn_r[w * 64 + ct * 16 + n16];
    }
    #pragma unroll
    for (int rt = 0; rt < 4; rt++) {
        #pragma unroll
        for (int reg = 0; reg < 4; reg++) {
            const int row = row0 + rt * 16 + quad * 4 + reg;
            const bool ok = row < N_NODES;
            float pl = 0.f, pr = 0.f;
            #pragma unroll
            for (int ct = 0; ct < 4; ct++) {
                const float v = acc[rt][ct][reg];
                if (ok) feat[(size_t)row * HF + w * 64 + ct * 16 + n16] = f2bf(v);
                pl = fmaf(v, alv[ct], pl);
                pr = fmaf(v, arv[ct], pr);
            }
            #pragma unroll
            for (int m = 8; m >= 1; m >>= 1) {
                pl += __shfl_xor(pl, m);
                pr += __shfl_xor(pr, m);
            }
            if (n16 == 0 && ok) {
                el[row * H_HEADS + w] = pl;
                er[row * H_HEADS + w] = pr;
            }
        }
    }
}

// ======================= fused prep: everything except agg =======================
__global__ __launch_bounds__(256, 3) void fused_prep(
    const float* __restrict__ nfeat, const float* __restrict__ fc_w,
    const float* __restrict__ fc_e_w, const float* __restrict__ attn_l,
    const float* __restrict__ attn_r, const float* __restrict__ attn_e,
    const float* __restrict__ edge_emb,
    const int* __restrict__ src, const int* __restrict__ dst, const int* __restrict__ etype,
    ushort_t* __restrict__ feat, float* __restrict__ el, float* __restrict__ er,
    float* __restrict__ ee, ushort_t* __restrict__ Bt, int* __restrict__ ip)
{
    int* deg     = ip + DEG_IOFF;
    int* cursor  = ip + CURSOR_IOFF;
    int* row_off = ip + ROWOFF_IOFF;
    int* ssrc    = ip + SSRC_IOFF;
    int* sety    = ip + SETY_IOFF;
    int* eidA    = ip + EID_IOFF;
    int* bar     = ip + BAR_IOFF;
    int* part    = ip + PART_IOFF;

    const int b = blockIdx.x, t = threadIdx.x;
    const int gt = b * 256 + t;
    const int GSTRIDE = NBLK * 256;

    // --- barrier init gate (ws is re-poisoned 0xAA before every launch) ---
    if (b == 0 && t == 0) {
        for (int i = 0; i < 34; i++) bar[i] = 0;
        __threadfence();
        __hip_atomic_store(bar + 34, MAGIC, __ATOMIC_RELEASE, __HIP_MEMORY_SCOPE_AGENT);
    }

    // --- phase Z: zero deg/cursor, cast Bt, ee ---
    for (int i = gt; i < 2 * N_NODES; i += GSTRIDE) deg[i] = 0;   // deg+cursor adjacent
    for (int i = gt; i < 65536; i += GSTRIDE) {
        const int k = i >> 8, c = i & 255;
        Bt[(size_t)c * 256 + k] = f2bf(fc_w[i]);
    }
    if (b == 1) {
        const float ae = attn_e[t];
        const int lane = t & 63, h = t >> 6;
        for (int ty = 0; ty < NT_TYPES; ty++) {
            float v = 0.f;
            #pragma unroll 8
            for (int k = 0; k < EF_DIM; k++)
                v = fmaf(edge_emb[ty * EF_DIM + k], fc_e_w[k * (H_HEADS * EF_DIM) + t], v);
            float contrib = v * ae;
            #pragma unroll
            for (int m = 32; m >= 1; m >>= 1) contrib += __shfl_xor(contrib, m);
            if (lane == 0) ee[ty * H_HEADS + h] = contrib;
        }
    }

    if (t == 0) {
        while (__hip_atomic_load(bar + 34, __ATOMIC_ACQUIRE, __HIP_MEMORY_SCOPE_AGENT) != MAGIC)
            __builtin_amdgcn_s_sleep(2);
    }
    bar_sync(bar);   // Z -> A

    // --- phase A: gemm (782 tiles) + hist ---
    for (int tile = b; tile < (N_NODES + 63) / 64; tile += NBLK)
        gemm_body(nfeat, Bt, attn_l, attn_r, feat, el, er, tile);
    for (int i = gt; i < E_EDGES; i += GSTRIDE)
        atomicAdd(deg + dst[i], 1);

    bar_sync(bar);   // A -> B1

    // --- phase B1: block-local scan of CHUNK deg values ---
    __shared__ int sscan[128];
    const int g0 = b * CHUNK;
    int dv = 0, local_excl = 0;
    {
        const int g = g0 + t;
        if (t < 128) {
            dv = (t < CHUNK && g < N_NODES) ? deg[g] : 0;
            sscan[t] = dv;
        }
        __syncthreads();
        for (int o = 1; o < 128; o <<= 1) {
            int v = 0;
            if (t < 128 && t >= o) v = sscan[t - o];
            __syncthreads();
            if (t < 128) sscan[t] += v;
            __syncthreads();
        }
        if (t < 128) local_excl = sscan[t] - dv;
        if (t == 127) part[b] = sscan[127];
    }

    bar_sync(bar);   // B1 -> B2

    // --- phase B2: block 0 scans NBLK partials -> exclusive ---
    if (b == 0) {
        __shared__ int s2[256];
        const int p0 = part[2 * t], p1 = part[2 * t + 1];
        const int tot = p0 + p1;
        s2[t] = tot;
        __syncthreads();
        int val = tot;
        for (int o = 1; o < 256; o <<= 1) {
            int v = (t >= o) ? s2[t - o] : 0;
            __syncthreads();
            val += v;
            s2[t] = val;
            __syncthreads();
        }
        const int excl = val - tot;
        part[2 * t] = excl;
        part[2 * t + 1] = excl + p0;
    }

    bar_sync(bar);   // B2 -> B3

    // --- phase B3: final row_off ---
    {
        const int base = part[b];
        const int g = g0 + t;
        if (t < CHUNK && g < N_NODES) row_off[g] = base + local_excl;
        if (b == 0 && t == 0) row_off[N_NODES] = E_EDGES;
    }

    bar_sync(bar);   // B3 -> C

    // --- phase C: scatter into dst-sorted arrays ---
    for (int i = gt; i < E_EDGES; i += GSTRIDE) {
        const int d = dst[i];
        const int pos = row_off[d] + atomicAdd(cursor + d, 1);
        ssrc[pos] = src[i];
        sety[pos] = etype[i];
        eidA[pos] = i;
    }

    if (b == 0 && t == 0)
        __hip_atomic_store(bar + 34, 0, __ATOMIC_RELEASE, __HIP_MEMORY_SCOPE_AGENT);
}

// ======================= agg: fused softmax + aggregation =======================
__global__ __launch_bounds__(256) void agg_kernel(
    const int* __restrict__ ssrc, const int* __restrict__ sety, const int* __restrict__ eidA,
    const int* __restrict__ row_off,
    const float* __restrict__ el, const float* __restrict__ er,
    const float* __restrict__ ee, const ushort_t* __restrict__ feat,
    float* __restrict__ a_out, float* __restrict__ rst)
{
    const int d = blockIdx.x;
    const int t = threadIdx.x;
    const int h = t >> 6, lane = t & 63;
    const int off = row_off[d];
    const int deg = row_off[d + 1] - off;

    __shared__ int sS[256];
    __shared__ int sE[256];
    __shared__ float sc[4][256];

    if (deg <= 256) {
        if (t < deg) {
            const int s  = ssrc[off + t];
            const int ty = sety[off + t];
            sS[t] = s;
            sE[t] = eidA[off + t];
            const float4 el4 = *(const float4*)(el + s * 4);
            const float4 er4 = *(const float4*)(er + d * 4);
            const float4 ee4 = *(const float4*)(ee + ty * 4);
            float v;
            v = el4.x + er4.x + ee4.x; sc[0][t] = v > 0.f ? v : SLOPE * v;
            v = el4.y + er4.y + ee4.y; sc[1][t] = v > 0.f ? v : SLOPE * v;
            v = el4.z + er4.z + ee4.z; sc[2][t] = v > 0.f ? v : SLOPE * v;
            v = el4.w + er4.w + ee4.w; sc[3][t] = v > 0.f ? v : SLOPE * v;
        }
        __syncthreads();

        float m = -INFINITY;
        for (int i = lane; i < deg; i += 64) m = fmaxf(m, sc[h][i]);
        #pragma unroll
        for (int w = 32; w >= 1; w >>= 1) m = fmaxf(m, __shfl_xor(m, w));

        float s = 0.f;
        for (int i = lane; i < deg; i += 64) s += __expf(sc[h][i] - m);
        #pragma unroll
        for (int w = 32; w >= 1; w >>= 1) s += __shfl_xor(s, w);
        const float inv = 1.f / s;

        for (int i = lane; i < deg; i += 64) {
            const float a = __expf(sc[h][i] - m) * inv;
            sc[h][i] = a;
            a_out[sE[i] * 4 + h] = a;
        }

        const ushort_t* fb = feat + h * 64 + lane;
        float acc = 0.f;
        int i = 0;
        for (; i + 4 <= deg; i += 4) {
            const int s0 = sS[i], s1 = sS[i + 1], s2 = sS[i + 2], s3 = sS[i + 3];
            const float a0 = sc[h][i], a1 = sc[h][i + 1], a2 = sc[h][i + 2], a3 = sc[h][i + 3];
            const float v0 = bf2f(fb[(size_t)s0 * HF]);
            const float v1 = bf2f(fb[(size_t)s1 * HF]);
            const float v2 = bf2f(fb[(size_t)s2 * HF]);
            const float v3 = bf2f(fb[(size_t)s3 * HF]);
            acc = fmaf(a0, v0, acc);
            acc = fmaf(a1, v1, acc);
            acc = fmaf(a2, v2, acc);
            acc = fmaf(a3, v3, acc);
        }
        for (; i < deg; i++)
            acc = fmaf(sc[h][i], bf2f(fb[(size_t)sS[i] * HF]), acc);
        rst[(size_t)d * HF + h * 64 + lane] = acc;
    } else {
        const float erh = er[d * 4 + h];
        float m = -INFINITY;
        for (int i = lane; i < deg; i += 64) {
            float v = el[ssrc[off + i] * 4 + h] + erh + ee[sety[off + i] * 4 + h];
            v = v > 0.f ? v : SLOPE * v;
            m = fmaxf(m, v);
        }
        #pragma unroll
        for (int w = 32; w >= 1; w >>= 1) m = fmaxf(m, __shfl_xor(m, w));
        float s = 0.f;
        for (int i = lane; i < deg; i += 64) {
            float v = el[ssrc[off + i] * 4 + h] + erh + ee[sety[off + i] * 4 + h];
            v = v > 0.f ? v : SLOPE * v;
            s += __expf(v - m);
        }
        #pragma unroll
        for (int w = 32; w >= 1; w >>= 1) s += __shfl_xor(s, w);
        const float inv = 1.f / s;
        float acc = 0.f;
        for (int i = 0; i < deg; i++) {
            const int sn = ssrc[off + i];
            float v = el[sn * 4 + h] + erh + ee[sety[off + i] * 4 + h];
            v = v > 0.f ? v : SLOPE * v;
            const float a = __expf(v - m) * inv;
            if (lane == 0) a_out[eidA[off + i] * 4 + h] = a;
            acc = fmaf(a, bf2f(feat[(size_t)sn * HF + h * 64 + lane]), acc);
        }
        rst[(size_t)d * HF + h * 64 + lane] = acc;
    }
}

extern "C" void kernel_launch(void* const* d_in, const int* in_sizes, int n_in,
                              void* d_out, int out_size, void* d_ws, size_t ws_size,
                              hipStream_t stream) {
    const float* nfeat    = (const float*)d_in[0];
    const float* fc_w     = (const float*)d_in[1];
    const float* fc_e_w   = (const float*)d_in[2];
    const float* attn_l   = (const float*)d_in[3];
    const float* attn_r   = (const float*)d_in[4];
    const float* attn_e   = (const float*)d_in[5];
    const float* edge_emb = (const float*)d_in[6];
    const int*   src      = (const int*)d_in[7];
    const int*   dst      = (const int*)d_in[8];
    const int*   etype    = (const int*)d_in[9];

    float* ws = (float*)d_ws;
    ushort_t* feat = (ushort_t*)(ws + FEATBF_OFF);
    float* el   = ws + EL_OFF;
    float* er   = ws + ER_OFF;
    float* ee   = ws + EE_OFF;
    ushort_t* Bt = (ushort_t*)(ws + BT_OFF);
    int*   ip   = (int*)(ws + INT_OFF);

    float* rst   = (float*)d_out;                              // [N,H,F]
    float* a_out = (float*)d_out + (size_t)N_NODES * HF;       // [E,H]

    fused_prep<<<NBLK, 256, 0, stream>>>(nfeat, fc_w, fc_e_w, attn_l, attn_r, attn_e,
                                         edge_emb, src, dst, etype,
                                         feat, el, er, ee, Bt, ip);

    agg_kernel<<<N_NODES, 256, 0, stream>>>(ip + SSRC_IOFF, ip + SETY_IOFF, ip + EID_IOFF,
                                            ip + ROWOFF_IOFF, el, er, ee, feat, a_out, rst);
}

// Round 6
// 457.889 us; speedup vs baseline: 1.7551x; 1.7551x over previous
//
#include <hip/hip_runtime.h>

#define N_NODES 50000
#define E_EDGES 800000
#define IN_DIM 256
#define H_HEADS 4
#define F_OUT 64
#define EF_DIM 64
#define NT_TYPES 8
#define SLOPE 0.2f
#define HF 256  /* H*F */

typedef __attribute__((ext_vector_type(8))) short short8;
typedef __attribute__((ext_vector_type(4))) float f32x4;
typedef unsigned short ushort_t;
typedef unsigned long long u64;

// workspace layout (float element offsets)
#define FEATBF_OFF 0          /* N*HF bf16 = 6.4M floats */
#define EL_OFF   6400000
#define ER_OFF   6600000
#define EE_OFF   6800000
#define BT_OFF   6800064      /* 256x256 bf16 = 32768 floats */
#define INT_OFF  6832832
// int offsets within int region
#define DEG_IOFF     0        /* 50,000 */
#define CURSOR_IOFF  50000    /* 50,000 (adjacent: one memset) */
#define ROWOFF_IOFF  100000   /* 50,001 -> pad 50,008 */
#define PK_IOFF      150008   /* packed edges: 800,000 u64 = 1.6M ints (8B aligned) */

#define NBLK_GEMM 782         /* ceil(50000/64) */
#define NBLK_HIST 3125        /* 800000/256 */

__device__ __forceinline__ ushort_t f2bf(float f) {
    unsigned u = __float_as_uint(f);
    u += 0x7fffu + ((u >> 16) & 1u);   // round-nearest-even
    return (ushort_t)(u >> 16);
}
__device__ __forceinline__ float bf2f(ushort_t b) {
    return __uint_as_float(((unsigned)b) << 16);
}

// ======================= K1: ee + cast_w =======================
__global__ __launch_bounds__(256) void k1_prep(
    const float* __restrict__ edge_emb, const float* __restrict__ fc_e_w,
    const float* __restrict__ attn_e, const float* __restrict__ fc_w,
    float* __restrict__ ee, ushort_t* __restrict__ Bt)
{
    const int b = blockIdx.x;
    if (b == 0) {
        const int c = threadIdx.x;
        const float ae = attn_e[c];
        const int lane = c & 63, h = c >> 6;
        for (int ty = 0; ty < NT_TYPES; ty++) {
            float v = 0.f;
            #pragma unroll 8
            for (int k = 0; k < EF_DIM; k++)
                v = fmaf(edge_emb[ty * EF_DIM + k], fc_e_w[k * (H_HEADS * EF_DIM) + c], v);
            float contrib = v * ae;
            #pragma unroll
            for (int m = 32; m >= 1; m >>= 1) contrib += __shfl_xor(contrib, m);
            if (lane == 0) ee[ty * H_HEADS + h] = contrib;
        }
    } else {
        const int k = b - 1, c = threadIdx.x;
        Bt[(size_t)c * 256 + k] = f2bf(fc_w[(size_t)k * 256 + c]);
    }
}

// ======================= K2: MFMA GEMM || hist =======================
__device__ __forceinline__ void gemm_body(
    const float* __restrict__ nfeat, const ushort_t* __restrict__ Bt,
    const float* __restrict__ attn_l, const float* __restrict__ attn_r,
    ushort_t* __restrict__ feat, float* __restrict__ el, float* __restrict__ er,
    int blk)
{
    const int w    = threadIdx.x >> 6;
    const int lane = threadIdx.x & 63;
    const int n16  = lane & 15;
    const int quad = lane >> 4;
    const int row0 = blk * 64;

    f32x4 acc[4][4];
    #pragma unroll
    for (int rt = 0; rt < 4; rt++)
        #pragma unroll
        for (int ct = 0; ct < 4; ct++)
            acc[rt][ct] = (f32x4){0.f, 0.f, 0.f, 0.f};

    for (int kb = 0; kb < IN_DIM; kb += 32) {
        short8 a[4], b[4];
        #pragma unroll
        for (int rt = 0; rt < 4; rt++) {
            int r = row0 + rt * 16 + n16;
            r = r < N_NODES ? r : N_NODES - 1;
            const float* p = nfeat + (size_t)r * IN_DIM + kb + quad * 8;
            const float4 v0 = *(const float4*)p;
            const float4 v1 = *(const float4*)(p + 4);
            short8 t;
            t[0] = (short)f2bf(v0.x); t[1] = (short)f2bf(v0.y);
            t[2] = (short)f2bf(v0.z); t[3] = (short)f2bf(v0.w);
            t[4] = (short)f2bf(v1.x); t[5] = (short)f2bf(v1.y);
            t[6] = (short)f2bf(v1.z); t[7] = (short)f2bf(v1.w);
            a[rt] = t;
        }
        #pragma unroll
        for (int ct = 0; ct < 4; ct++) {
            const int c = w * 64 + ct * 16 + n16;
            b[ct] = *(const short8*)(Bt + (size_t)c * 256 + kb + quad * 8);
        }
        #pragma unroll
        for (int rt = 0; rt < 4; rt++)
            #pragma unroll
            for (int ct = 0; ct < 4; ct++)
                acc[rt][ct] = __builtin_amdgcn_mfma_f32_16x16x32_bf16(a[rt], b[ct], acc[rt][ct], 0, 0, 0);
    }

    float alv[4], arv[4];
    #pragma unroll
    for (int ct = 0; ct < 4; ct++) {
        alv[ct] = attn_l[w * 64 + ct * 16 + n16];
        arv[ct] = attn_r[w * 64 + ct * 16 + n16];
    }
    #pragma unroll
    for (int rt = 0; rt < 4; rt++) {
        #pragma unroll
        for (int reg = 0; reg < 4; reg++) {
            const int row = row0 + rt * 16 + quad * 4 + reg;
            const bool ok = row < N_NODES;
            float pl = 0.f, pr = 0.f;
            #pragma unroll
            for (int ct = 0; ct < 4; ct++) {
                const float v = acc[rt][ct][reg];
                if (ok) feat[(size_t)row * HF + w * 64 + ct * 16 + n16] = f2bf(v);
                pl = fmaf(v, alv[ct], pl);
                pr = fmaf(v, arv[ct], pr);
            }
            #pragma unroll
            for (int m = 8; m >= 1; m >>= 1) {
                pl += __shfl_xor(pl, m);
                pr += __shfl_xor(pr, m);
            }
            if (n16 == 0 && ok) {
                el[row * H_HEADS + w] = pl;
                er[row * H_HEADS + w] = pr;
            }
        }
    }
}

__global__ __launch_bounds__(256) void k2_gemm_hist(
    const float* __restrict__ nfeat, const ushort_t* __restrict__ Bt,
    const float* __restrict__ attn_l, const float* __restrict__ attn_r,
    ushort_t* __restrict__ feat, float* __restrict__ el, float* __restrict__ er,
    const int* __restrict__ dst, int* __restrict__ deg)
{
    if (blockIdx.x < NBLK_GEMM) {
        gemm_body(nfeat, Bt, attn_l, attn_r, feat, el, er, blockIdx.x);
    } else {
        const int t = (blockIdx.x - NBLK_GEMM) * 256 + threadIdx.x;
        if (t < E_EDGES) atomicAdd(deg + dst[t], 1);
    }
}

// ======================= K3: block-wide scan (1 block, 1024 threads) =======================
#define SCAN_CH 49  /* 1024*49 >= 50000 */
__global__ __launch_bounds__(1024) void scan_kernel(
    const int* __restrict__ deg, int* __restrict__ row_off)
{
    __shared__ int part[1024];
    const int t = threadIdx.x;
    const int start = t * SCAN_CH;
    int s = 0;
    for (int j = 0; j < SCAN_CH; j++) {
        const int g = start + j;
        if (g < N_NODES) s += deg[g];
    }
    part[t] = s;
    __syncthreads();
    int val = s;
    for (int o = 1; o < 1024; o <<= 1) {
        int v = (t >= o) ? part[t - o] : 0;
        __syncthreads();
        val += v;
        part[t] = val;
        __syncthreads();
    }
    int running = val - s;  // exclusive prefix
    for (int j = 0; j < SCAN_CH; j++) {
        const int g = start + j;
        if (g >= N_NODES) break;
        row_off[g] = running;
        running += deg[g];
    }
    if (start <= N_NODES && N_NODES < start + SCAN_CH) row_off[N_NODES] = running;
}

// ======================= K4: scatter -> packed dst-sorted edge array =======================
// pack = src(16b) | etype(8b) << 16 | eid << 32   -> single 8B store per edge
__global__ __launch_bounds__(256) void scatter_kernel(
    const int* __restrict__ src, const int* __restrict__ dst, const int* __restrict__ etype,
    const int* __restrict__ row_off, int* __restrict__ cursor, u64* __restrict__ pk)
{
    const int t = blockIdx.x * 256 + threadIdx.x;
    if (t >= E_EDGES) return;
    const int d = dst[t];
    const int pos = row_off[d] + atomicAdd(cursor + d, 1);
    pk[pos] = (u64)src[t] | ((u64)etype[t] << 16) | ((u64)t << 32);
}

// ======================= K5: fused softmax + aggregation (v3) =======================
__global__ __launch_bounds__(256) void agg_kernel(
    const u64* __restrict__ pk, const int* __restrict__ row_off,
    const float* __restrict__ el, const float* __restrict__ er,
    const float* __restrict__ ee, const ushort_t* __restrict__ feat,
    float* __restrict__ a_out, float* __restrict__ rst)
{
    const int d = blockIdx.x;
    const int t = threadIdx.x;
    const int h = t >> 6, lane = t & 63;
    const int off = row_off[d];
    const int deg = row_off[d + 1] - off;

    __shared__ int sS[256];
    __shared__ int sE[256];
    __shared__ float sc[4][256];

    if (deg <= 256) {
        if (t < deg) {
            const u64 p = pk[off + t];
            const int s  = (int)(p & 0xffffu);
            const int ty = (int)((p >> 16) & 0xffu);
            sS[t] = s;
            sE[t] = (int)(p >> 32);
            const float4 el4 = *(const float4*)(el + s * 4);
            const float4 er4 = *(const float4*)(er + d * 4);
            const float4 ee4 = *(const float4*)(ee + ty * 4);
            float v;
            v = el4.x + er4.x + ee4.x; sc[0][t] = v > 0.f ? v : SLOPE * v;
            v = el4.y + er4.y + ee4.y; sc[1][t] = v > 0.f ? v : SLOPE * v;
            v = el4.z + er4.z + ee4.z; sc[2][t] = v > 0.f ? v : SLOPE * v;
            v = el4.w + er4.w + ee4.w; sc[3][t] = v > 0.f ? v : SLOPE * v;
        }
        __syncthreads();

        float m = -INFINITY;
        for (int i = lane; i < deg; i += 64) m = fmaxf(m, sc[h][i]);
        #pragma unroll
        for (int w = 32; w >= 1; w >>= 1) m = fmaxf(m, __shfl_xor(m, w));

        float s = 0.f;
        for (int i = lane; i < deg; i += 64) s += __expf(sc[h][i] - m);
        #pragma unroll
        for (int w = 32; w >= 1; w >>= 1) s += __shfl_xor(s, w);
        const float inv = 1.f / s;

        // normalize in LDS (component h touched only by wave h)
        for (int i = lane; i < deg; i += 64) {
            const float a = __expf(sc[h][i] - m) * inv;
            sc[h][i] = a;
            a_out[sE[i] * 4 + h] = a;
        }

        // aggregation: half-wave per edge, u32 loads (2 packed bf16 per lane)
        const int half = lane >> 5;        // 0: edge i, 1: edge i+1
        const int l32  = lane & 31;
        const unsigned* fb32 = (const unsigned*)feat;  // feat row s: 128 u32; head h: +h*32
        float accL = 0.f, accH = 0.f;      // f = 2*l32, 2*l32+1
        int i = 0;
        for (; i + 2 <= deg; i += 2) {
            const int idx = i + half;
            const int sn = sS[idx];
            const float a = sc[h][idx];
            const unsigned u = fb32[sn * 128 + h * 32 + l32];
            accL = fmaf(a, __uint_as_float(u << 16), accL);
            accH = fmaf(a, __uint_as_float(u & 0xffff0000u), accH);
        }
        if (i < deg && half == 0) {        // odd tail: half 0 handles it
            const int sn = sS[i];
            const float a = sc[h][i];
            const unsigned u = fb32[sn * 128 + h * 32 + l32];
            accL = fmaf(a, __uint_as_float(u << 16), accL);
            accH = fmaf(a, __uint_as_float(u & 0xffff0000u), accH);
        }
        accL += __shfl_xor(accL, 32);
        accH += __shfl_xor(accH, 32);
        if (half == 0) {
            float2 o = {accL, accH};
            *(float2*)(rst + (size_t)d * HF + h * 64 + l32 * 2) = o;
        }
    } else {
        // fallback for deg > 256
        const float erh = er[d * 4 + h];
        float m = -INFINITY;
        for (int i = lane; i < deg; i += 64) {
            const u64 p = pk[off + i];
            float v = el[(int)(p & 0xffffu) * 4 + h] + erh + ee[(int)((p >> 16) & 0xffu) * 4 + h];
            v = v > 0.f ? v : SLOPE * v;
            m = fmaxf(m, v);
        }
        #pragma unroll
        for (int w = 32; w >= 1; w >>= 1) m = fmaxf(m, __shfl_xor(m, w));
        float s = 0.f;
        for (int i = lane; i < deg; i += 64) {
            const u64 p = pk[off + i];
            float v = el[(int)(p & 0xffffu) * 4 + h] + erh + ee[(int)((p >> 16) & 0xffu) * 4 + h];
            v = v > 0.f ? v : SLOPE * v;
            s += __expf(v - m);
        }
        #pragma unroll
        for (int w = 32; w >= 1; w >>= 1) s += __shfl_xor(s, w);
        const float inv = 1.f / s;
        float acc = 0.f;
        for (int i = 0; i < deg; i++) {
            const u64 p = pk[off + i];
            const int sn = (int)(p & 0xffffu);
            float v = el[sn * 4 + h] + erh + ee[(int)((p >> 16) & 0xffu) * 4 + h];
            v = v > 0.f ? v : SLOPE * v;
            const float a = __expf(v - m) * inv;
            if (lane == 0) a_out[(int)(p >> 32) * 4 + h] = a;
            acc = fmaf(a, bf2f(feat[(size_t)sn * HF + h * 64 + lane]), acc);
        }
        rst[(size_t)d * HF + h * 64 + lane] = acc;
    }
}

extern "C" void kernel_launch(void* const* d_in, const int* in_sizes, int n_in,
                              void* d_out, int out_size, void* d_ws, size_t ws_size,
                              hipStream_t stream) {
    const float* nfeat    = (const float*)d_in[0];
    const float* fc_w     = (const float*)d_in[1];
    const float* fc_e_w   = (const float*)d_in[2];
    const float* attn_l   = (const float*)d_in[3];
    const float* attn_r   = (const float*)d_in[4];
    const float* attn_e   = (const float*)d_in[5];
    const float* edge_emb = (const float*)d_in[6];
    const int*   src      = (const int*)d_in[7];
    const int*   dst      = (const int*)d_in[8];
    const int*   etype    = (const int*)d_in[9];

    float* ws = (float*)d_ws;
    ushort_t* feat = (ushort_t*)(ws + FEATBF_OFF);
    float* el   = ws + EL_OFF;
    float* er   = ws + ER_OFF;
    float* ee   = ws + EE_OFF;
    ushort_t* Bt = (ushort_t*)(ws + BT_OFF);
    int*   ip      = (int*)(ws + INT_OFF);
    int*   deg     = ip + DEG_IOFF;
    int*   cursor  = ip + CURSOR_IOFF;
    int*   row_off = ip + ROWOFF_IOFF;
    u64*   pk      = (u64*)(ip + PK_IOFF);

    float* rst   = (float*)d_out;                              // [N,H,F]
    float* a_out = (float*)d_out + (size_t)N_NODES * HF;       // [E,H]

    hipMemsetAsync(deg, 0, 2 * N_NODES * sizeof(int), stream);

    k1_prep<<<257, 256, 0, stream>>>(edge_emb, fc_e_w, attn_e, fc_w, ee, Bt);
    k2_gemm_hist<<<NBLK_GEMM + NBLK_HIST, 256, 0, stream>>>(
        nfeat, Bt, attn_l, attn_r, feat, el, er, dst, deg);
    scan_kernel<<<1, 1024, 0, stream>>>(deg, row_off);
    scatter_kernel<<<NBLK_HIST, 256, 0, stream>>>(src, dst, etype, row_off, cursor, pk);
    agg_kernel<<<N_NODES, 256, 0, stream>>>(pk, row_off, el, er, ee, feat, a_out, rst);
}

// Round 7
// 418.098 us; speedup vs baseline: 1.9222x; 1.0952x over previous
//
#include <hip/hip_runtime.h>

#define N_NODES 50000
#define E_EDGES 800000
#define IN_DIM 256
#define H_HEADS 4
#define F_OUT 64
#define EF_DIM 64
#define NT_TYPES 8
#define SLOPE 0.2f
#define HF 256  /* H*F */

typedef __attribute__((ext_vector_type(8))) short short8;
typedef __attribute__((ext_vector_type(4))) float f32x4;
typedef unsigned short ushort_t;
typedef unsigned long long u64;

// workspace layout (float element offsets)
#define FEATBF_OFF 0          /* N*HF bf16 = 6.4M floats */
#define EL_OFF   6400000
#define ER_OFF   6600000
#define EE_OFF   6800000
#define BT_OFF   6800064      /* 256x256 bf16 = 32768 floats */
#define INT_OFF  6832832
// int offsets within int region
#define DEG_IOFF     0        /* 50,000 */
#define CURSOR_IOFF  50000    /* 50,000 (adjacent: zeroed together) */
#define ROWOFF_IOFF  100000   /* 50,001 -> pad 50,008 */
#define PK_IOFF      150008   /* packed edges: 800,000 u64 (8B aligned) */

#define NBLK_GEMM 782         /* ceil(50000/64) */
#define NBLK_HIST 3125        /* 800000/256 */

__device__ __forceinline__ ushort_t f2bf(float f) {
    unsigned u = __float_as_uint(f);
    u += 0x7fffu + ((u >> 16) & 1u);   // round-nearest-even
    return (ushort_t)(u >> 16);
}
__device__ __forceinline__ float bf2f(ushort_t b) {
    return __uint_as_float(((unsigned)b) << 16);
}

// ======================= K1: ee + cast_w + zero(deg,cursor) =======================
__global__ __launch_bounds__(256) void k1_prep(
    const float* __restrict__ edge_emb, const float* __restrict__ fc_e_w,
    const float* __restrict__ attn_e, const float* __restrict__ fc_w,
    float* __restrict__ ee, ushort_t* __restrict__ Bt, int* __restrict__ zero_region)
{
    const int b = blockIdx.x;
    if (b == 0) {
        const int c = threadIdx.x;
        const float ae = attn_e[c];
        const int lane = c & 63, h = c >> 6;
        for (int ty = 0; ty < NT_TYPES; ty++) {
            float v = 0.f;
            #pragma unroll 8
            for (int k = 0; k < EF_DIM; k++)
                v = fmaf(edge_emb[ty * EF_DIM + k], fc_e_w[k * (H_HEADS * EF_DIM) + c], v);
            float contrib = v * ae;
            #pragma unroll
            for (int m = 32; m >= 1; m >>= 1) contrib += __shfl_xor(contrib, m);
            if (lane == 0) ee[ty * H_HEADS + h] = contrib;
        }
    } else if (b <= 256) {
        const int k = b - 1, c = threadIdx.x;
        Bt[(size_t)c * 256 + k] = f2bf(fc_w[(size_t)k * 256 + c]);
    } else {
        const int idx = (b - 257) * 256 + threadIdx.x;
        if (idx < 2 * N_NODES) zero_region[idx] = 0;   // deg + cursor adjacent
    }
}

// ======================= K2: MFMA GEMM || hist =======================
__device__ __forceinline__ void gemm_body(
    const float* __restrict__ nfeat, const ushort_t* __restrict__ Bt,
    const float* __restrict__ attn_l, const float* __restrict__ attn_r,
    ushort_t* __restrict__ feat, float* __restrict__ el, float* __restrict__ er,
    int blk)
{
    const int w    = threadIdx.x >> 6;
    const int lane = threadIdx.x & 63;
    const int n16  = lane & 15;
    const int quad = lane >> 4;
    const int row0 = blk * 64;

    f32x4 acc[4][4];
    #pragma unroll
    for (int rt = 0; rt < 4; rt++)
        #pragma unroll
        for (int ct = 0; ct < 4; ct++)
            acc[rt][ct] = (f32x4){0.f, 0.f, 0.f, 0.f};

    for (int kb = 0; kb < IN_DIM; kb += 32) {
        short8 a[4], b[4];
        #pragma unroll
        for (int rt = 0; rt < 4; rt++) {
            int r = row0 + rt * 16 + n16;
            r = r < N_NODES ? r : N_NODES - 1;
            const float* p = nfeat + (size_t)r * IN_DIM + kb + quad * 8;
            const float4 v0 = *(const float4*)p;
            const float4 v1 = *(const float4*)(p + 4);
            short8 t;
            t[0] = (short)f2bf(v0.x); t[1] = (short)f2bf(v0.y);
            t[2] = (short)f2bf(v0.z); t[3] = (short)f2bf(v0.w);
            t[4] = (short)f2bf(v1.x); t[5] = (short)f2bf(v1.y);
            t[6] = (short)f2bf(v1.z); t[7] = (short)f2bf(v1.w);
            a[rt] = t;
        }
        #pragma unroll
        for (int ct = 0; ct < 4; ct++) {
            const int c = w * 64 + ct * 16 + n16;
            b[ct] = *(const short8*)(Bt + (size_t)c * 256 + kb + quad * 8);
        }
        #pragma unroll
        for (int rt = 0; rt < 4; rt++)
            #pragma unroll
            for (int ct = 0; ct < 4; ct++)
                acc[rt][ct] = __builtin_amdgcn_mfma_f32_16x16x32_bf16(a[rt], b[ct], acc[rt][ct], 0, 0, 0);
    }

    float alv[4], arv[4];
    #pragma unroll
    for (int ct = 0; ct < 4; ct++) {
        alv[ct] = attn_l[w * 64 + ct * 16 + n16];
        arv[ct] = attn_r[w * 64 + ct * 16 + n16];
    }
    #pragma unroll
    for (int rt = 0; rt < 4; rt++) {
        #pragma unroll
        for (int reg = 0; reg < 4; reg++) {
            const int row = row0 + rt * 16 + quad * 4 + reg;
            const bool ok = row < N_NODES;
            float pl = 0.f, pr = 0.f;
            #pragma unroll
            for (int ct = 0; ct < 4; ct++) {
                const float v = acc[rt][ct][reg];
                if (ok) feat[(size_t)row * HF + w * 64 + ct * 16 + n16] = f2bf(v);
                pl = fmaf(v, alv[ct], pl);
                pr = fmaf(v, arv[ct], pr);
            }
            #pragma unroll
            for (int m = 8; m >= 1; m >>= 1) {
                pl += __shfl_xor(pl, m);
                pr += __shfl_xor(pr, m);
            }
            if (n16 == 0 && ok) {
                el[row * H_HEADS + w] = pl;
                er[row * H_HEADS + w] = pr;
            }
        }
    }
}

__global__ __launch_bounds__(256) void k2_gemm_hist(
    const float* __restrict__ nfeat, const ushort_t* __restrict__ Bt,
    const float* __restrict__ attn_l, const float* __restrict__ attn_r,
    ushort_t* __restrict__ feat, float* __restrict__ el, float* __restrict__ er,
    const int* __restrict__ dst, int* __restrict__ deg)
{
    if (blockIdx.x < NBLK_GEMM) {
        gemm_body(nfeat, Bt, attn_l, attn_r, feat, el, er, blockIdx.x);
    } else {
        const int t = (blockIdx.x - NBLK_GEMM) * 256 + threadIdx.x;
        if (t < E_EDGES) atomicAdd(deg + dst[t], 1);
    }
}

// ======================= K3: block-wide scan (1 block, 1024 threads) =======================
#define SCAN_CH 49  /* 1024*49 >= 50000 */
__global__ __launch_bounds__(1024) void scan_kernel(
    const int* __restrict__ deg, int* __restrict__ row_off)
{
    __shared__ int part[1024];
    const int t = threadIdx.x;
    const int start = t * SCAN_CH;
    int s = 0;
    for (int j = 0; j < SCAN_CH; j++) {
        const int g = start + j;
        if (g < N_NODES) s += deg[g];
    }
    part[t] = s;
    __syncthreads();
    int val = s;
    for (int o = 1; o < 1024; o <<= 1) {
        int v = (t >= o) ? part[t - o] : 0;
        __syncthreads();
        val += v;
        part[t] = val;
        __syncthreads();
    }
    int running = val - s;  // exclusive prefix
    for (int j = 0; j < SCAN_CH; j++) {
        const int g = start + j;
        if (g >= N_NODES) break;
        row_off[g] = running;
        running += deg[g];
    }
    if (start <= N_NODES && N_NODES < start + SCAN_CH) row_off[N_NODES] = running;
}

// ======================= K4: scatter -> packed dst-sorted edge array =======================
// pack = src(16b) | etype(8b) << 16 | eid << 32   -> single 8B store per edge
__global__ __launch_bounds__(256) void scatter_kernel(
    const int* __restrict__ src, const int* __restrict__ dst, const int* __restrict__ etype,
    const int* __restrict__ row_off, int* __restrict__ cursor, u64* __restrict__ pk)
{
    const int t = blockIdx.x * 256 + threadIdx.x;
    if (t >= E_EDGES) return;
    const int d = dst[t];
    const int pos = row_off[d] + atomicAdd(cursor + d, 1);
    pk[pos] = (u64)src[t] | ((u64)etype[t] << 16) | ((u64)t << 32);
}

// ======================= K5: fused softmax + aggregation (v4) =======================
__global__ __launch_bounds__(256) void agg_kernel(
    const u64* __restrict__ pk, const int* __restrict__ row_off,
    const float* __restrict__ el, const float* __restrict__ er,
    const float* __restrict__ ee, const ushort_t* __restrict__ feat,
    float* __restrict__ a_out, float* __restrict__ rst)
{
    const int d = blockIdx.x;
    const int t = threadIdx.x;
    const int h = t >> 6, lane = t & 63;
    const int off = row_off[d];
    const int deg = row_off[d + 1] - off;

    __shared__ int sS[256];
    __shared__ int sE[256];
    __shared__ float sc[4][256];

    if (deg <= 248) {                      // degP <= 256 guaranteed
        const int degP = (deg + 7) & ~7;   // pad to multiple of 8 with zero-weight edges
        if (t < deg) {
            const u64 p = pk[off + t];
            const int s  = (int)(p & 0xffffu);
            const int ty = (int)((p >> 16) & 0xffu);
            sS[t] = s;
            sE[t] = (int)(p >> 32);
            const float4 el4 = *(const float4*)(el + s * 4);
            const float4 er4 = *(const float4*)(er + d * 4);
            const float4 ee4 = *(const float4*)(ee + ty * 4);
            float v;
            v = el4.x + er4.x + ee4.x; sc[0][t] = v > 0.f ? v : SLOPE * v;
            v = el4.y + er4.y + ee4.y; sc[1][t] = v > 0.f ? v : SLOPE * v;
            v = el4.z + er4.z + ee4.z; sc[2][t] = v > 0.f ? v : SLOPE * v;
            v = el4.w + er4.w + ee4.w; sc[3][t] = v > 0.f ? v : SLOPE * v;
        } else if (t < degP) {
            sS[t] = 0;                     // zero-weight pad -> row 0 (L2-hot), contributes 0
            sc[0][t] = 0.f; sc[1][t] = 0.f; sc[2][t] = 0.f; sc[3][t] = 0.f;
        }
        __syncthreads();

        float m = -INFINITY;
        for (int i = lane; i < deg; i += 64) m = fmaxf(m, sc[h][i]);
        #pragma unroll
        for (int w = 32; w >= 1; w >>= 1) m = fmaxf(m, __shfl_xor(m, w));

        float s = 0.f;
        for (int i = lane; i < deg; i += 64) s += __expf(sc[h][i] - m);
        #pragma unroll
        for (int w = 32; w >= 1; w >>= 1) s += __shfl_xor(s, w);
        const float inv = 1.f / s;

        // normalize in LDS (component h touched only by wave h); pads stay 0
        for (int i = lane; i < deg; i += 64) {
            const float a = __expf(sc[h][i] - m) * inv;
            sc[h][i] = a;
            a_out[sE[i] * 4 + h] = a;
        }

        // aggregation: half-wave per edge, u32 loads, 4 independent gathers in flight
        const int half = lane >> 5;        // 0: even edge, 1: odd edge
        const int l32  = lane & 31;
        const unsigned* fb32 = (const unsigned*)feat;   // row s: 128 u32; head h: +h*32
        float accL = 0.f, accH = 0.f;      // f = 2*l32, 2*l32+1
        for (int i = 0; i < degP; i += 8) {
            int sn[4]; float aw[4];
            #pragma unroll
            for (int j = 0; j < 4; j++) {
                const int idx = i + j * 2 + half;
                sn[j] = sS[idx];
                aw[j] = sc[h][idx];
            }
            unsigned u[4];
            #pragma unroll
            for (int j = 0; j < 4; j++)
                u[j] = fb32[sn[j] * 128 + h * 32 + l32];
            #pragma unroll
            for (int j = 0; j < 4; j++) {
                accL = fmaf(aw[j], __uint_as_float(u[j] << 16), accL);
                accH = fmaf(aw[j], __uint_as_float(u[j] & 0xffff0000u), accH);
            }
        }
        accL += __shfl_xor(accL, 32);
        accH += __shfl_xor(accH, 32);
        if (half == 0) {
            float2 o = {accL, accH};
            *(float2*)(rst + (size_t)d * HF + h * 64 + l32 * 2) = o;
        }
    } else {
        // fallback for large deg
        const float erh = er[d * 4 + h];
        float m = -INFINITY;
        for (int i = lane; i < deg; i += 64) {
            const u64 p = pk[off + i];
            float v = el[(int)(p & 0xffffu) * 4 + h] + erh + ee[(int)((p >> 16) & 0xffu) * 4 + h];
            v = v > 0.f ? v : SLOPE * v;
            m = fmaxf(m, v);
        }
        #pragma unroll
        for (int w = 32; w >= 1; w >>= 1) m = fmaxf(m, __shfl_xor(m, w));
        float s = 0.f;
        for (int i = lane; i < deg; i += 64) {
            const u64 p = pk[off + i];
            float v = el[(int)(p & 0xffffu) * 4 + h] + erh + ee[(int)((p >> 16) & 0xffu) * 4 + h];
            v = v > 0.f ? v : SLOPE * v;
            s += __expf(v - m);
        }
        #pragma unroll
        for (int w = 32; w >= 1; w >>= 1) s += __shfl_xor(s, w);
        const float inv = 1.f / s;
        float acc = 0.f;
        for (int i = 0; i < deg; i++) {
            const u64 p = pk[off + i];
            const int sn = (int)(p & 0xffffu);
            float v = el[sn * 4 + h] + erh + ee[(int)((p >> 16) & 0xffu) * 4 + h];
            v = v > 0.f ? v : SLOPE * v;
            const float a = __expf(v - m) * inv;
            if (lane == 0) a_out[(int)(p >> 32) * 4 + h] = a;
            acc = fmaf(a, bf2f(feat[(size_t)sn * HF + h * 64 + lane]), acc);
        }
        rst[(size_t)d * HF + h * 64 + lane] = acc;
    }
}

extern "C" void kernel_launch(void* const* d_in, const int* in_sizes, int n_in,
                              void* d_out, int out_size, void* d_ws, size_t ws_size,
                              hipStream_t stream) {
    const float* nfeat    = (const float*)d_in[0];
    const float* fc_w     = (const float*)d_in[1];
    const float* fc_e_w   = (const float*)d_in[2];
    const float* attn_l   = (const float*)d_in[3];
    const float* attn_r   = (const float*)d_in[4];
    const float* attn_e   = (const float*)d_in[5];
    const float* edge_emb = (const float*)d_in[6];
    const int*   src      = (const int*)d_in[7];
    const int*   dst      = (const int*)d_in[8];
    const int*   etype    = (const int*)d_in[9];

    float* ws = (float*)d_ws;
    ushort_t* feat = (ushort_t*)(ws + FEATBF_OFF);
    float* el   = ws + EL_OFF;
    float* er   = ws + ER_OFF;
    float* ee   = ws + EE_OFF;
    ushort_t* Bt = (ushort_t*)(ws + BT_OFF);
    int*   ip      = (int*)(ws + INT_OFF);
    int*   deg     = ip + DEG_IOFF;
    int*   cursor  = ip + CURSOR_IOFF;
    int*   row_off = ip + ROWOFF_IOFF;
    u64*   pk      = (u64*)(ip + PK_IOFF);

    float* rst   = (float*)d_out;                              // [N,H,F]
    float* a_out = (float*)d_out + (size_t)N_NODES * HF;       // [E,H]

    // K1: ee (1 blk) + cast_w (256) + zero deg/cursor (391)
    k1_prep<<<648, 256, 0, stream>>>(edge_emb, fc_e_w, attn_e, fc_w, ee, Bt, deg);
    k2_gemm_hist<<<NBLK_GEMM + NBLK_HIST, 256, 0, stream>>>(
        nfeat, Bt, attn_l, attn_r, feat, el, er, dst, deg);
    scan_kernel<<<1, 1024, 0, stream>>>(deg, row_off);
    scatter_kernel<<<NBLK_HIST, 256, 0, stream>>>(src, dst, etype, row_off, cursor, pk);
    agg_kernel<<<N_NODES, 256, 0, stream>>>(pk, row_off, el, er, ee, feat, a_out, rst);
}